// Round 2
// baseline (291.092 us; speedup 1.0000x reference)
//
#include <hip/hip_runtime.h>
#include <hip/hip_bf16.h>

// GNNBlock: 3-layer DenseGAT, B=512 graphs x N=128 nodes, HEADS=4, HID=64.
// adj is all-ones (mask no-op). One block per graph; all activations live in
// LDS across the 3 layers. bf16 MFMA (16x16x32) for both X@W and P@V.
// Weights pre-transposed to bf16 W^T[n][k] in d_ws by prep_w (L2-resident).

typedef unsigned short u16;
typedef __attribute__((ext_vector_type(8))) short short8;
typedef __attribute__((ext_vector_type(4))) float f32x4;
typedef __attribute__((ext_vector_type(4))) unsigned short u16x4;

#define NEG_SLOPE 0.2f
#define L2E 1.44269504088896340736f

__device__ __forceinline__ u16 f2bf(float f) {
  unsigned int u = __float_as_uint(f);
  u += 0x7fffu + ((u >> 16) & 1u);   // round-to-nearest-even
  return (u16)(u >> 16);
}
__device__ __forceinline__ float bf2f(u16 s) {
  return __uint_as_float(((unsigned int)s) << 16);
}

// LDS byte offsets with XOR swizzle (G4: break row-stride bank conflicts).
// Xs: [128 rows][256 bf16] row stride 512B. Ht: [256 rows][128 bf16] stride 256B.
__device__ __forceinline__ int xs_byte(int row, int col) {
  return (row << 9) + ((col << 1) ^ ((row & 7) << 4));
}
__device__ __forceinline__ int ht_byte(int row, int col) {
  return (row << 8) + ((col << 1) ^ ((row & 7) << 4));
}

__global__ void prep_w(const float* __restrict__ W0, const float* __restrict__ W1,
                       const float* __restrict__ W2, u16* __restrict__ wt) {
  int gid = blockIdx.x * 256 + threadIdx.x;
  if (gid < 32768) {                       // Wt0 [256][128]
    int n = gid >> 7, k = gid & 127;
    wt[gid] = f2bf(W0[k * 256 + n]);
  } else if (gid < 98304) {                // Wt1 [256][256]
    int idx = gid - 32768;
    int n = idx >> 8, k = idx & 255;
    wt[gid] = f2bf(W1[k * 256 + n]);
  } else if (gid < 163840) {               // Wt2 [256][256]
    int idx = gid - 98304;
    int n = idx >> 8, k = idx & 255;
    wt[gid] = f2bf(W2[k * 256 + n]);
  }
}

__global__ __launch_bounds__(512, 2) void gat_all(
    const float* __restrict__ x, const u16* __restrict__ wtall,
    const float* __restrict__ as0, const float* __restrict__ ad0, const float* __restrict__ bb0,
    const float* __restrict__ as1, const float* __restrict__ ad1, const float* __restrict__ bb1,
    const float* __restrict__ as2, const float* __restrict__ ad2, const float* __restrict__ bb2,
    float* __restrict__ out)
{
  constexpr int XS_OFF = 0;                 // 64KB  activations (bf16)
  constexpr int HT_OFF = 65536;             // 64KB  H^T (bf16)
  constexpr int SB_OFF = 131072;            // s[4][128] f32
  constexpr int DB_OFF = SB_OFF + 2048;     // d[4][128]
  constexpr int ML_OFF = DB_OFF + 2048;     // rowmax*log2e
  constexpr int RB_OFF = ML_OFF + 2048;     // 1/denom
  constexpr int AS_OFF = RB_OFF + 2048;     // att_src [256] f32
  constexpr int AD_OFF = AS_OFF + 1024;     // att_dst
  constexpr int BS_OFF = AD_OFF + 1024;     // bias
  constexpr int OA_OFF = BS_OFF + 1024;     // output accum [256] f32
  __shared__ unsigned char smem[OA_OFF + 1024];   // 140KB total

  float* sbuf = (float*)(smem + SB_OFF);
  float* dbuf = (float*)(smem + DB_OFF);
  float* mlb  = (float*)(smem + ML_OFF);
  float* rbf  = (float*)(smem + RB_OFF);
  float* asb  = (float*)(smem + AS_OFF);
  float* adb  = (float*)(smem + AD_OFF);
  float* bsb  = (float*)(smem + BS_OFF);
  float* oac  = (float*)(smem + OA_OFF);

  const int b    = blockIdx.x;
  const int tid  = threadIdx.x;
  const int w    = tid >> 6;
  const int lane = tid & 63;
  const int l15  = lane & 15;
  const int lg   = lane >> 4;

  // ---- load X_b (128x128 f32) -> bf16 LDS ----
  {
    const float4* xg = (const float4*)(x + (size_t)b * (128 * 128));
    #pragma unroll
    for (int it = 0; it < 8; ++it) {
      int e = tid + it * 512;               // 4096 float4 total
      float4 v = xg[e];
      int row = e >> 5;                     // 32 float4 per row
      int c = (e & 31) << 2;
      u16x4 u = {f2bf(v.x), f2bf(v.y), f2bf(v.z), f2bf(v.w)};
      *(u16x4*)(smem + XS_OFF + xs_byte(row, c)) = u;
    }
  }

  const float* aspv[3] = {as0, as1, as2};
  const float* adpv[3] = {ad0, ad1, ad2};
  const float* bpv[3]  = {bb0, bb1, bb2};
  const u16*   wtp[3]  = {wtall, wtall + 32768, wtall + 98304};
  const int    Kv[3]   = {128, 256, 256};

  #pragma unroll
  for (int l = 0; l < 3; ++l) {
    const int K = Kv[l];
    // stage per-layer vectors
    if (tid < 256) {
      asb[tid] = aspv[l][tid];
      adb[tid] = adpv[l][tid];
      bsb[tid] = bpv[l][tid];
      if (l == 2) oac[tid] = 0.f;
    }
    __syncthreads();

    // ---- GEMM: H = X @ W ; write H^T into Ht ----
    {
      const int mw = w & 1, nw = w >> 1;    // 2(M) x 4(N) wave grid, 64x64 tiles
      f32x4 acc[4][4];
      #pragma unroll
      for (int mi = 0; mi < 4; ++mi)
        #pragma unroll
        for (int ni = 0; ni < 4; ++ni)
          acc[mi][ni] = (f32x4){0.f, 0.f, 0.f, 0.f};
      const u16* wtl = wtp[l];
      #pragma unroll
      for (int ks = 0; ks < K / 32; ++ks) {
        const int kcol = ks * 32 + lg * 8;
        short8 afr[4], bfr[4];
        #pragma unroll
        for (int mi = 0; mi < 4; ++mi) {
          int row = mw * 64 + mi * 16 + l15;
          afr[mi] = *(const short8*)(smem + XS_OFF + xs_byte(row, kcol));
        }
        #pragma unroll
        for (int ni = 0; ni < 4; ++ni) {
          int n = nw * 64 + ni * 16 + l15;
          bfr[ni] = *(const short8*)(wtl + n * K + kcol);   // L2-resident
        }
        #pragma unroll
        for (int mi = 0; mi < 4; ++mi)
          #pragma unroll
          for (int ni = 0; ni < 4; ++ni)
            acc[mi][ni] = __builtin_amdgcn_mfma_f32_16x16x32_bf16(
                afr[mi], bfr[ni], acc[mi][ni], 0, 0, 0);
      }
      // epilogue: D row=(lg*4+reg)=node j, col=l15=feature c. Write Ht[c][j].
      #pragma unroll
      for (int mi = 0; mi < 4; ++mi) {
        int jrow = mw * 64 + mi * 16 + lg * 4;
        #pragma unroll
        for (int ni = 0; ni < 4; ++ni) {
          int c = nw * 64 + ni * 16 + l15;
          u16x4 u = {f2bf(acc[mi][ni][0]), f2bf(acc[mi][ni][1]),
                     f2bf(acc[mi][ni][2]), f2bf(acc[mi][ni][3])};
          *(u16x4*)(smem + HT_OFF + ht_byte(c, jrow)) = u;
        }
      }
    }
    __syncthreads();

    // ---- s/d dots: s[h][j]=H[j]·att_src[h], d[h][i]=H[i]·att_dst[h] ----
    {
      const int h = tid >> 7, j = tid & 127;
      float s0 = 0.f, d0 = 0.f;
      #pragma unroll 8
      for (int c = 0; c < 64; ++c) {
        float hv = bf2f(*(const u16*)(smem + HT_OFF + ht_byte(h * 64 + c, j)));
        s0 = fmaf(hv, asb[h * 64 + c], s0);
        d0 = fmaf(hv, adb[h * 64 + c], d0);
      }
      sbuf[tid] = s0;
      dbuf[tid] = d0;
    }
    __syncthreads();

    // ---- softmax stats per (h,i): rowmax & 1/denom of LR(s[j]+d[i]) ----
    {
      const int h = tid >> 7;
      float dv = dbuf[tid];
      float mx = -3.4e38f;
      #pragma unroll 8
      for (int jj = 0; jj < 128; ++jj) {
        float v = sbuf[h * 128 + jj] + dv;
        v = v >= 0.f ? v : NEG_SLOPE * v;
        mx = fmaxf(mx, v);
      }
      float den = 0.f;
      #pragma unroll 8
      for (int jj = 0; jj < 128; ++jj) {
        float v = sbuf[h * 128 + jj] + dv;
        v = v >= 0.f ? v : NEG_SLOPE * v;
        den += exp2f((v - mx) * L2E);
      }
      mlb[tid] = mx * L2E;
      rbf[tid] = 1.f / den;
    }
    __syncthreads();

    // ---- PV: out^T = H_head^T @ P^T, P generated on the fly ----
    {
      const int hw = w >> 1, iw = w & 1;    // head, node-half
      f32x4 acc[4][4];
      #pragma unroll
      for (int mi = 0; mi < 4; ++mi)
        #pragma unroll
        for (int ni = 0; ni < 4; ++ni)
          acc[mi][ni] = (f32x4){0.f, 0.f, 0.f, 0.f};
      float dvv[4], mlv[4], rvv[4];
      #pragma unroll
      for (int ni = 0; ni < 4; ++ni) {
        int i = iw * 64 + ni * 16 + l15;
        dvv[ni] = dbuf[hw * 128 + i];
        mlv[ni] = mlb[hw * 128 + i];
        rvv[ni] = rbf[hw * 128 + i];
      }
      #pragma unroll
      for (int ks = 0; ks < 4; ++ks) {
        const int j0 = ks * 32 + lg * 8;
        short8 afr[4], bfr[4];
        #pragma unroll
        for (int mi = 0; mi < 4; ++mi)
          afr[mi] = *(const short8*)(smem + HT_OFF + ht_byte(hw * 64 + mi * 16 + l15, j0));
        #pragma unroll
        for (int ni = 0; ni < 4; ++ni) {
          short8 pv;
          #pragma unroll
          for (int jj = 0; jj < 8; ++jj) {
            float v = sbuf[hw * 128 + j0 + jj] + dvv[ni];
            v = v >= 0.f ? v : NEG_SLOPE * v;
            float p = exp2f(fmaf(v, L2E, -mlv[ni])) * rvv[ni];
            pv[jj] = (short)f2bf(p);
          }
          bfr[ni] = pv;
        }
        #pragma unroll
        for (int mi = 0; mi < 4; ++mi)
          #pragma unroll
          for (int ni = 0; ni < 4; ++ni)
            acc[mi][ni] = __builtin_amdgcn_mfma_f32_16x16x32_bf16(
                afr[mi], bfr[ni], acc[mi][ni], 0, 0, 0);
      }
      if (l < 2) {
        // D row = feature c (consecutive via reg), col = node i. bias + write next X.
        #pragma unroll
        for (int mi = 0; mi < 4; ++mi) {
          #pragma unroll
          for (int ni = 0; ni < 4; ++ni) {
            int i = iw * 64 + ni * 16 + l15;
            int c = hw * 64 + mi * 16 + lg * 4;
            u16x4 u = {f2bf(acc[mi][ni][0] + bsb[c + 0]),
                       f2bf(acc[mi][ni][1] + bsb[c + 1]),
                       f2bf(acc[mi][ni][2] + bsb[c + 2]),
                       f2bf(acc[mi][ni][3] + bsb[c + 3])};
            *(u16x4*)(smem + XS_OFF + xs_byte(i, c)) = u;
          }
        }
      } else {
        // final layer: sum over nodes i. Sum frags over ni, butterfly over l15.
        #pragma unroll
        for (int mi = 0; mi < 4; ++mi) {
          #pragma unroll
          for (int reg = 0; reg < 4; ++reg) {
            float p = acc[mi][0][reg] + acc[mi][1][reg] + acc[mi][2][reg] + acc[mi][3][reg];
            p += __shfl_xor(p, 1);
            p += __shfl_xor(p, 2);
            p += __shfl_xor(p, 4);
            p += __shfl_xor(p, 8);
            if (l15 == 0)
              atomicAdd(&oac[hw * 64 + mi * 16 + lg * 4 + reg], p);
          }
        }
      }
    }
    __syncthreads();
  }

  // bias summed over 128 nodes = 128*b[c]
  if (tid < 256) out[(size_t)b * 256 + tid] = oac[tid] + 128.f * bsb[tid];
}

extern "C" void kernel_launch(void* const* d_in, const int* in_sizes, int n_in,
                              void* d_out, int out_size, void* d_ws, size_t ws_size,
                              hipStream_t stream) {
  const float* x   = (const float*)d_in[0];
  // d_in[1] = batch_mask (unused: uniform graph layout)
  const float* W0  = (const float*)d_in[2];
  const float* as0 = (const float*)d_in[3];
  const float* ad0 = (const float*)d_in[4];
  const float* b0  = (const float*)d_in[5];
  const float* W1  = (const float*)d_in[6];
  const float* as1 = (const float*)d_in[7];
  const float* ad1 = (const float*)d_in[8];
  const float* b1  = (const float*)d_in[9];
  const float* W2  = (const float*)d_in[10];
  const float* as2 = (const float*)d_in[11];
  const float* ad2 = (const float*)d_in[12];
  const float* b2  = (const float*)d_in[13];
  u16* wt = (u16*)d_ws;                      // 327,680 bytes used

  hipLaunchKernelGGL(prep_w, dim3(640), dim3(256), 0, stream, W0, W1, W2, wt);
  hipLaunchKernelGGL(gat_all, dim3(512), dim3(512), 0, stream,
                     x, wt, as0, ad0, b0, as1, ad1, b1, as2, ad2, b2,
                     (float*)d_out);
}

// Round 4
// 207.277 us; speedup vs baseline: 1.4044x; 1.4044x over previous
//
#include <hip/hip_runtime.h>
#include <hip/hip_bf16.h>

// GNNBlock: 3-layer DenseGAT, B=512 graphs x N=128 nodes, HEADS=4, HID=64.
// adj all-ones. One 1024-thread block per graph; activations in LDS all 3
// layers. bf16 MFMA for X@W, s/d projections, and P@V. Weights stored
// fragment-ready (coalesced) in d_ws; s/d use precomputed W·att vectors.
// Softmax max via monotone-LR trick: max_j LR(s_j+d_i) = LR(max_j s_j + d_i).

typedef unsigned short u16;
typedef __attribute__((ext_vector_type(8))) short short8;
typedef __attribute__((ext_vector_type(4))) float f32x4;

#define L2E 1.44269504088896340736f

__device__ __forceinline__ u16 f2bf(float f) {
  unsigned int u = __float_as_uint(f);
  u += 0x7fffu + ((u >> 16) & 1u);   // RNE
  return (u16)(u >> 16);
}
__device__ __forceinline__ unsigned int pk2(float a, float b) {
  __hip_bfloat162 h2 = __float22bfloat162_rn(make_float2(a, b));
  unsigned int u;
  __builtin_memcpy(&u, &h2, 4);
  return u;
}

// LDS byte offsets with XOR swizzle (G4).
// Xs: [128 rows][256 bf16] stride 512B. Ht: [256 rows][128 bf16] stride 256B.
__device__ __forceinline__ int xs_byte(int row, int col) {
  return (row << 9) + ((col << 1) ^ ((row & 7) << 4));
}
__device__ __forceinline__ int ht_byte(int row, int col) {
  return (row << 8) + ((col << 1) ^ ((row & 7) << 4));
}

// d_ws layout (bf16 elements):
//   [0)       Wfrag L0: 16 ntiles x 4 kb x 64 lane x 8   = 32768
//   [32768)   Wfrag L1: 16 x 8 x 64 x 8                  = 65536
//   [98304)   Wfrag L2:                                   = 65536
//   [163840)  wsd L0: 4 kb x 64 lane x 8 (cols: ws0-3, wd0-3, 0) = 2048
//   [165888)  wsd L1: 8 x 64 x 8                          = 4096
//   [169984)  wsd L2:                                     = 4096
//   total 174080 elems = 348160 B
__global__ void prep_w(const float* __restrict__ W0, const float* __restrict__ W1,
                       const float* __restrict__ W2,
                       const float* __restrict__ as0, const float* __restrict__ ad0,
                       const float* __restrict__ as1, const float* __restrict__ ad1,
                       const float* __restrict__ as2, const float* __restrict__ ad2,
                       u16* __restrict__ wt) {
  int gid = blockIdx.x * 256 + threadIdx.x;
  if (gid < 163840) {
    const float* W; int nkb, base;
    if (gid < 32768)      { W = W0; nkb = 4; base = 0; }
    else if (gid < 98304) { W = W1; nkb = 8; base = 32768; }
    else                  { W = W2; nkb = 8; base = 98304; }
    int idx  = gid - base;
    int e    = idx & 7;
    int lane = (idx >> 3) & 63;
    int rest = idx >> 9;                    // t*nkb + kb
    int t = rest / nkb, kb = rest - t * nkb;
    int n = t * 16 + (lane & 15);
    int k = kb * 32 + (lane >> 4) * 8 + e;
    wt[gid] = f2bf(W[k * 256 + n]);
  } else if (gid < 174080) {
    int idx = gid - 163840;
    const float* W; const float* as; const float* ad; int base2;
    if (idx < 2048)      { W = W0; as = as0; ad = ad0; base2 = 0; }
    else if (idx < 6144) { W = W1; as = as1; ad = ad1; base2 = 2048; }
    else                 { W = W2; as = as2; ad = ad2; base2 = 6144; }
    int i2 = idx - base2;
    int e = i2 & 7, lane = (i2 >> 3) & 63, kb = i2 >> 9;
    int l15 = lane & 15;
    int k = kb * 32 + (lane >> 4) * 8 + e;
    float v = 0.f;
    if (l15 < 8) {
      const float* av = (l15 < 4) ? as : ad;
      int h = l15 & 3;
      for (int c = 0; c < 64; ++c)
        v = fmaf(W[k * 256 + h * 64 + c], av[h * 64 + c], v);
    }
    wt[gid] = f2bf(v);
  }
}

__global__ __launch_bounds__(1024, 4) void gat_all(
    const float* __restrict__ x, const u16* __restrict__ wt,
    const float* __restrict__ bb0, const float* __restrict__ bb1,
    const float* __restrict__ bb2, float* __restrict__ out)
{
  constexpr int XS = 0;               // 64KB activations bf16 (swizzled)
  constexpr int HT = 65536;           // 64KB H^T bf16 (swizzled)
  constexpr int SB = 131072;          // s[4][128] f32
  constexpr int DB = 133120;          // d[4][128] f32
  constexpr int ML = 135168;          // ml[4][128] f32 (rowmax*L2E, post-LR)
  constexpr int PT = 137216;          // den partials [2][512] f32
  constexpr int PM = 141312;          // per-wave s-max [4][8] f32
  constexpr int BS = 141440;          // bias [256] f32
  constexpr int OA = 142464;          // out accum [256] f32
  __shared__ unsigned char smem[143488];

  float* sbuf  = (float*)(smem + SB);
  float* dbuf  = (float*)(smem + DB);
  float* mlb   = (float*)(smem + ML);
  float* ptmp  = (float*)(smem + PT);
  float* pmaxw = (float*)(smem + PM);
  float* bsb   = (float*)(smem + BS);
  float* oac   = (float*)(smem + OA);

  const int b    = blockIdx.x;
  const int tid  = threadIdx.x;
  const int w    = tid >> 6;          // 16 waves
  const int lane = tid & 63;
  const int l15  = lane & 15;
  const int lg   = lane >> 4;

  // ---- load X_b (128x128 f32) -> bf16 LDS ----
  {
    const float4* xg = (const float4*)(x + (size_t)b * (128 * 128));
    #pragma unroll
    for (int it = 0; it < 4; ++it) {
      int e = tid + it * 1024;        // 4096 float4 total
      float4 v = xg[e];
      int row = e >> 5, c = (e & 31) << 2;
      uint2 u = { pk2(v.x, v.y), pk2(v.z, v.w) };
      *(uint2*)(smem + XS + xs_byte(row, c)) = u;
    }
  }
  __syncthreads();

  const u16* wfl[3]   = {wt, wt + 32768, wt + 98304};
  const u16* wsdp[3]  = {wt + 163840, wt + 165888, wt + 169984};
  const float* bias[3] = {bb0, bb1, bb2};

  #pragma unroll
  for (int l = 0; l < 3; ++l) {
    const int NKB = (l == 0) ? 4 : 8;       // K/32

    // ---- A: GEMM H = X @ W -> Ht (16 waves: 2M x 8N, 64x32 tiles) ----
    if (tid < 256) bsb[tid] = bias[l][tid];
    {
      const int mw = w & 1, nw = w >> 1;
      f32x4 acc[4][2] = {};
      const u16* wf = wfl[l];
      #pragma unroll
      for (int ks = 0; ks < NKB; ++ks) {
        const int kcol = ks * 32 + lg * 8;
        short8 afr[4];
        #pragma unroll
        for (int mi = 0; mi < 4; ++mi)
          afr[mi] = *(const short8*)(smem + XS + xs_byte(mw * 64 + mi * 16 + l15, kcol));
        short8 bfr[2];
        #pragma unroll
        for (int ni = 0; ni < 2; ++ni) {
          int t = nw * 2 + ni;
          bfr[ni] = *(const short8*)(wf + (((t * NKB + ks) * 64 + lane) << 3));
        }
        #pragma unroll
        for (int mi = 0; mi < 4; ++mi)
          #pragma unroll
          for (int ni = 0; ni < 2; ++ni)
            acc[mi][ni] = __builtin_amdgcn_mfma_f32_16x16x32_bf16(
                afr[mi], bfr[ni], acc[mi][ni], 0, 0, 0);
      }
      // D: row=node j (lg*4+reg), col=feature c (l15). Write Ht[c][j..j+3].
      #pragma unroll
      for (int mi = 0; mi < 4; ++mi) {
        int j0 = mw * 64 + mi * 16 + lg * 4;
        #pragma unroll
        for (int ni = 0; ni < 2; ++ni) {
          int c = nw * 32 + ni * 16 + l15;
          uint2 u = { pk2(acc[mi][ni][0], acc[mi][ni][1]),
                      pk2(acc[mi][ni][2], acc[mi][ni][3]) };
          *(uint2*)(smem + HT + ht_byte(c, j0)) = u;
        }
      }
    }
    __syncthreads();

    // ---- B: s/d via MFMA (waves 0..7; cols 0-3 = s heads, 4-7 = d heads) ----
    if (w < 8) {
      f32x4 acc = {};
      const u16* wv = wsdp[l];
      #pragma unroll
      for (int ks = 0; ks < NKB; ++ks) {
        int kcol = ks * 32 + lg * 8;
        short8 a = *(const short8*)(smem + XS + xs_byte(w * 16 + l15, kcol));
        short8 bq = *(const short8*)(wv + ((ks * 64 + lane) << 3));
        acc = __builtin_amdgcn_mfma_f32_16x16x32_bf16(a, bq, acc, 0, 0, 0);
      }
      if (l15 < 8) {
        float* basep = (float*)(smem + (l15 < 4 ? SB : DB)) + (l15 & 3) * 128 + w * 16 + lg * 4;
        *(float4*)basep = (float4){acc[0], acc[1], acc[2], acc[3]};
      }
      // per-(head,wave) max of s over this wave's 16 nodes (l15<4 lanes valid)
      float m = fmaxf(fmaxf(acc[0], acc[1]), fmaxf(acc[2], acc[3]));
      m = fmaxf(m, __shfl_xor(m, 16));
      m = fmaxf(m, __shfl_xor(m, 32));
      if (lg == 0 && l15 < 4) pmaxw[l15 * 8 + w] = m;
    }
    __syncthreads();

    // ---- D: denominator pass (1024 threads = 512 (h,i) pairs x 2 j-halves) ----
    {
      int p = tid & 511, half = tid >> 9;
      int h = p >> 7;
      float smax = pmaxw[h * 8];
      #pragma unroll
      for (int q2 = 1; q2 < 8; ++q2) smax = fmaxf(smax, pmaxw[h * 8 + q2]);
      float dv = dbuf[p];
      float mlr = smax + dv;
      mlr = fmaxf(mlr, 0.2f * mlr);           // LR monotone -> true row max
      float ml = mlr * L2E;
      const float* sr = sbuf + h * 128 + half * 64;
      float den0 = 0.f, den1 = 0.f;
      #pragma unroll 8
      for (int jj = 0; jj < 64; jj += 2) {
        float va = sr[jj] + dv, vb = sr[jj + 1] + dv;
        va = fmaxf(va, 0.2f * va);
        vb = fmaxf(vb, 0.2f * vb);
        den0 += exp2f(fmaf(va, L2E, -ml));
        den1 += exp2f(fmaf(vb, L2E, -ml));
      }
      ptmp[half * 512 + p] = den0 + den1;
      if (half == 0) mlb[p] = ml;
      if (l == 2 && tid < 256) oac[tid] = 0.f;
    }
    __syncthreads();

    // ---- F: PV  out^T = H_head^T @ P^T (16 waves: head x i-quarter) ----
    {
      const int hw = w >> 2, q = w & 3;
      f32x4 acc[4][2] = {};
      float dvv[2], mlv[2];
      int iblk[2];
      #pragma unroll
      for (int ni = 0; ni < 2; ++ni) {
        int i = q * 32 + ni * 16 + l15;
        iblk[ni] = hw * 128 + i;
        dvv[ni] = dbuf[iblk[ni]];
        mlv[ni] = mlb[iblk[ni]];
      }
      #pragma unroll
      for (int ks = 0; ks < 4; ++ks) {
        const int j0 = ks * 32 + lg * 8;
        float sj[8];
        #pragma unroll
        for (int jj = 0; jj < 8; ++jj) sj[jj] = sbuf[hw * 128 + j0 + jj];
        short8 afr[4];
        #pragma unroll
        for (int mi = 0; mi < 4; ++mi)
          afr[mi] = *(const short8*)(smem + HT + ht_byte(hw * 64 + mi * 16 + l15, j0));
        short8 bfr[2];
        #pragma unroll
        for (int ni = 0; ni < 2; ++ni) {
          float e[8];
          #pragma unroll
          for (int jj = 0; jj < 8; ++jj) {
            float v = sj[jj] + dvv[ni];
            v = fmaxf(v, 0.2f * v);
            e[jj] = exp2f(fmaf(v, L2E, -mlv[ni]));
          }
          union { short8 s; unsigned int u[4]; } pk;
          #pragma unroll
          for (int t2 = 0; t2 < 4; ++t2) pk.u[t2] = pk2(e[2 * t2], e[2 * t2 + 1]);
          bfr[ni] = pk.s;
        }
        #pragma unroll
        for (int mi = 0; mi < 4; ++mi)
          #pragma unroll
          for (int ni = 0; ni < 2; ++ni)
            acc[mi][ni] = __builtin_amdgcn_mfma_f32_16x16x32_bf16(
                afr[mi], bfr[ni], acc[mi][ni], 0, 0, 0);
      }
      float rvv[2];
      #pragma unroll
      for (int ni = 0; ni < 2; ++ni)
        rvv[ni] = 1.f / (ptmp[iblk[ni]] + ptmp[512 + iblk[ni]]);
      if (l < 2) {
        // D: row=feature c, col=node i. out = r_i*acc + bias -> next Xs.
        #pragma unroll
        for (int mi = 0; mi < 4; ++mi) {
          int c0 = hw * 64 + mi * 16 + lg * 4;
          float b0v = bsb[c0], b1v = bsb[c0 + 1], b2v = bsb[c0 + 2], b3v = bsb[c0 + 3];
          #pragma unroll
          for (int ni = 0; ni < 2; ++ni) {
            int i = q * 32 + ni * 16 + l15;
            float r = rvv[ni];
            uint2 u = { pk2(fmaf(acc[mi][ni][0], r, b0v), fmaf(acc[mi][ni][1], r, b1v)),
                        pk2(fmaf(acc[mi][ni][2], r, b2v), fmaf(acc[mi][ni][3], r, b3v)) };
            *(uint2*)(smem + XS + xs_byte(i, c0)) = u;
          }
        }
      } else {
        // final layer: sum over nodes i (ni-sum, shfl over l15, atomic over q)
        #pragma unroll
        for (int mi = 0; mi < 4; ++mi) {
          #pragma unroll
          for (int reg = 0; reg < 4; ++reg) {
            float pv2 = acc[mi][0][reg] * rvv[0] + acc[mi][1][reg] * rvv[1];
            pv2 += __shfl_xor(pv2, 1);
            pv2 += __shfl_xor(pv2, 2);
            pv2 += __shfl_xor(pv2, 4);
            pv2 += __shfl_xor(pv2, 8);
            if (l15 == 0)
              atomicAdd(&oac[hw * 64 + mi * 16 + lg * 4 + reg], pv2);
          }
        }
      }
    }
    __syncthreads();
  }

  // bias summed over 128 nodes = 128*b[c]
  if (tid < 256) out[(size_t)b * 256 + tid] = oac[tid] + 128.f * bsb[tid];
}

extern "C" void kernel_launch(void* const* d_in, const int* in_sizes, int n_in,
                              void* d_out, int out_size, void* d_ws, size_t ws_size,
                              hipStream_t stream) {
  const float* x   = (const float*)d_in[0];
  // d_in[1] = batch_mask (unused: uniform graph layout)
  const float* W0  = (const float*)d_in[2];
  const float* as0 = (const float*)d_in[3];
  const float* ad0 = (const float*)d_in[4];
  const float* b0  = (const float*)d_in[5];
  const float* W1  = (const float*)d_in[6];
  const float* as1 = (const float*)d_in[7];
  const float* ad1 = (const float*)d_in[8];
  const float* b1  = (const float*)d_in[9];
  const float* W2  = (const float*)d_in[10];
  const float* as2 = (const float*)d_in[11];
  const float* ad2 = (const float*)d_in[12];
  const float* b2  = (const float*)d_in[13];
  u16* wt = (u16*)d_ws;                      // 348,160 bytes used

  hipLaunchKernelGGL(prep_w, dim3(680), dim3(256), 0, stream,
                     W0, W1, W2, as0, ad0, as1, ad1, as2, ad2, wt);
  hipLaunchKernelGGL(gat_all, dim3(512), dim3(1024), 0, stream,
                     x, wt, b0, b1, b2, (float*)d_out);
}

// Round 6
// 174.419 us; speedup vs baseline: 1.6689x; 1.1884x over previous
//
#include <hip/hip_runtime.h>
#include <hip/hip_bf16.h>

// GNNBlock: 3-layer DenseGAT, B=512 graphs x N=128 nodes, HEADS=4, HID=64.
// adj all-ones. One 1024-thread block per graph; activations in LDS all 3
// layers. bf16 MFMA for X@W (+fused s/d projections as a 17th N-tile) and
// P@V (P generated on the fly; denominator accumulated in-register inside
// PV). 2 barriers per layer. Weights fragment-ready in d_ws (coalesced prep).

typedef unsigned short u16;
typedef __attribute__((ext_vector_type(8))) short short8;
typedef __attribute__((ext_vector_type(4))) float f32x4;

#define L2E 1.44269504088896340736f

__device__ __forceinline__ u16 f2bf(float f) {
  unsigned int u = __float_as_uint(f);
  u += 0x7fffu + ((u >> 16) & 1u);   // RNE
  return (u16)(u >> 16);
}
__device__ __forceinline__ unsigned int pk2(float a, float b) {
  __hip_bfloat162 h2 = __float22bfloat162_rn(make_float2(a, b));
  unsigned int u;
  __builtin_memcpy(&u, &h2, 4);
  return u;
}

// LDS byte offsets with XOR swizzle (G4).
// Xs: [128 rows][256 bf16] stride 512B. Ht: [256 rows][128 bf16] stride 256B.
__device__ __forceinline__ int xs_byte(int row, int col) {
  return (row << 9) + ((col << 1) ^ ((row & 7) << 4));
}
__device__ __forceinline__ int ht_byte(int row, int col) {
  return (row << 8) + ((col << 1) ^ ((row & 7) << 4));
}

// d_ws (bf16 elems): per layer, 17 N-tiles (16 weight + 1 wsd) of fragment
// data: elem = base + ((t*NKB + kb)*64 + lane)*8 + e.
//   L0: base 0      NKB=4  -> 34816 elems
//   L1: base 34816  NKB=8  -> 69632
//   L2: base 104448 NKB=8  -> 69632   total 174080 elems = 348160 B
__global__ void prep_w(const float* __restrict__ W0, const float* __restrict__ W1,
                       const float* __restrict__ W2,
                       const float* __restrict__ as0, const float* __restrict__ ad0,
                       const float* __restrict__ as1, const float* __restrict__ ad1,
                       const float* __restrict__ as2, const float* __restrict__ ad2,
                       u16* __restrict__ wt) {
  const int bid = blockIdx.x, tid = threadIdx.x;
  if (bid < 80) {
    // ---- part 1: W -> fragments. Block = 8 consecutive k-rows (kb,ko). ----
    const float* W; int NKB, base, rel;
    if (bid < 16)      { W = W0; NKB = 4; base = 0;      rel = bid; }
    else if (bid < 48) { W = W1; NKB = 8; base = 34816;  rel = bid - 16; }
    else               { W = W2; NKB = 8; base = 104448; rel = bid - 48; }
    const int kb = rel >> 2, ko = rel & 3;
    const int n = tid;
    union { u16 v[8]; short8 s; } u;
    #pragma unroll
    for (int e = 0; e < 8; ++e)
      u.v[e] = f2bf(W[(kb * 32 + ko * 8 + e) * 256 + n]);   // coalesced rows
    const int t = n >> 4, l15 = n & 15;
    *(short8*)(wt + base + (((t * NKB + kb) * 64 + l15 + (ko << 4)) << 3)) = u.s;
  } else if (bid < 100) {
    // ---- part 2: wsd = [W·att_src | W·att_dst | 0] tile (t=16). ----
    int b2 = bid - 80;
    const float* W; const float* as; const float* ad; int NKB, base, kb;
    if (b2 < 4)       { W = W0; as = as0; ad = ad0; NKB = 4; base = 0;      kb = b2; }
    else if (b2 < 12) { W = W1; as = as1; ad = ad1; NKB = 8; base = 34816;  kb = b2 - 4; }
    else              { W = W2; as = as2; ad = ad2; NKB = 8; base = 104448; kb = b2 - 12; }
    const int kloc = tid >> 3, col = tid & 7, h = col & 3;
    const int k = kb * 32 + kloc;
    const float* av = (col < 4) ? as : ad;
    float acc = 0.f;
    #pragma unroll 8
    for (int c = 0; c < 64; ++c)
      acc = fmaf(W[k * 256 + h * 64 + c], av[h * 64 + c], acc);
    const int lane2 = col + ((kloc >> 3) << 4), e = kloc & 7;
    const int tb = base + ((16 * NKB + kb) << 9);
    wt[tb + ((lane2) << 3) + e]     = f2bf(acc);
    wt[tb + ((lane2 + 8) << 3) + e] = 0;        // zero columns 8..15
  }
}

__global__ __launch_bounds__(1024, 4) void gat_all(
    const float* __restrict__ x, const u16* __restrict__ wt,
    const float* __restrict__ bb0, const float* __restrict__ bb1,
    const float* __restrict__ bb2, float* __restrict__ out)
{
  constexpr int XS = 0;               // 64KB activations bf16 (swizzled)
  constexpr int HT = 65536;           // 64KB H^T bf16 (swizzled)
  constexpr int SB = 131072;          // s[4][128]*L2E f32
  constexpr int DB = 133120;          // d[4][128]*L2E f32
  constexpr int PM = 135168;          // per-half s-max [4][2] f32 (scaled)
  constexpr int BS = 135232;          // bias [256] f32
  constexpr int OA = 136256;          // out accum [256] f32
  __shared__ unsigned char smem[137280];

  float* sbuf  = (float*)(smem + SB);
  float* dbuf  = (float*)(smem + DB);
  float* pmaxw = (float*)(smem + PM);
  float* bsb   = (float*)(smem + BS);
  float* oac   = (float*)(smem + OA);

  const int b    = blockIdx.x;
  const int tid  = threadIdx.x;
  const int w    = tid >> 6;          // 16 waves
  const int lane = tid & 63;
  const int l15  = lane & 15;
  const int lg   = lane >> 4;

  // ---- load X_b (128x128 f32) -> bf16 LDS ----
  {
    const float4* xg = (const float4*)(x + (size_t)b * (128 * 128));
    #pragma unroll
    for (int it = 0; it < 4; ++it) {
      int e = tid + it * 1024;        // 4096 float4 total
      float4 v = xg[e];
      int row = e >> 5, c = (e & 31) << 2;
      uint2 u = { pk2(v.x, v.y), pk2(v.z, v.w) };
      *(uint2*)(smem + XS + xs_byte(row, c)) = u;
    }
  }
  __syncthreads();

  const u16* wfl[3]    = {wt, wt + 34816, wt + 104448};
  const float* bias[3] = {bb0, bb1, bb2};

  #pragma unroll
  for (int l = 0; l < 3; ++l) {
    const int NKB = (l == 0) ? 4 : 8;       // K/32
    const u16* wf = wfl[l];

    // ---- A: GEMM H = X @ W -> Ht (16 waves: 2M x 8N, 64x32 tiles) ----
    if (tid < 256) {
      bsb[tid] = bias[l][tid];
      if (l == 2) oac[tid] = 0.f;
    }
    {
      const int mw = w & 1, nw = w >> 1;
      f32x4 acc[4][2] = {};
      for (int ks = 0; ks < NKB; ++ks) {
        const int kcol = ks * 32 + lg * 8;
        short8 afr[4];
        #pragma unroll
        for (int mi = 0; mi < 4; ++mi)
          afr[mi] = *(const short8*)(smem + XS + xs_byte(mw * 64 + mi * 16 + l15, kcol));
        short8 bfr[2];
        #pragma unroll
        for (int ni = 0; ni < 2; ++ni) {
          int t = nw * 2 + ni;
          bfr[ni] = *(const short8*)(wf + (((t * NKB + ks) * 64 + lane) << 3));
        }
        #pragma unroll
        for (int mi = 0; mi < 4; ++mi)
          #pragma unroll
          for (int ni = 0; ni < 2; ++ni)
            acc[mi][ni] = __builtin_amdgcn_mfma_f32_16x16x32_bf16(
                afr[mi], bfr[ni], acc[mi][ni], 0, 0, 0);
      }
      // D: row=node j (lg*4+reg), col=feature c (l15). Write Ht[c][j..j+3].
      #pragma unroll
      for (int mi = 0; mi < 4; ++mi) {
        int j0 = mw * 64 + mi * 16 + lg * 4;
        #pragma unroll
        for (int ni = 0; ni < 2; ++ni) {
          int c = nw * 32 + ni * 16 + l15;
          uint2 u = { pk2(acc[mi][ni][0], acc[mi][ni][1]),
                      pk2(acc[mi][ni][2], acc[mi][ni][3]) };
          *(uint2*)(smem + HT + ht_byte(c, j0)) = u;
        }
      }
    }

    // ---- A': fused s/d tile (t=16) on waves 14,15 only ----
    if (w >= 14) {
      const int mw = w & 1;
      f32x4 acc2[4] = {};
      for (int ks = 0; ks < NKB; ++ks) {
        const int kcol = ks * 32 + lg * 8;
        short8 bsd = *(const short8*)(wf + (((16 * NKB + ks) * 64 + lane) << 3));
        #pragma unroll
        for (int mi = 0; mi < 4; ++mi) {
          short8 a = *(const short8*)(smem + XS + xs_byte(mw * 64 + mi * 16 + l15, kcol));
          acc2[mi] = __builtin_amdgcn_mfma_f32_16x16x32_bf16(a, bsd, acc2[mi], 0, 0, 0);
        }
      }
      // scale by L2E; D col=l15: 0-3 s-heads, 4-7 d-heads; row=node j.
      float mx = -3.4e38f;
      #pragma unroll
      for (int mi = 0; mi < 4; ++mi) {
        f32x4 v = acc2[mi] * L2E;
        if (l15 < 8) {
          float* basep = (float*)(smem + (l15 < 4 ? SB : DB))
                       + (l15 & 3) * 128 + mw * 64 + mi * 16 + lg * 4;
          *(float4*)basep = (float4){v[0], v[1], v[2], v[3]};
        }
        mx = fmaxf(mx, fmaxf(fmaxf(v[0], v[1]), fmaxf(v[2], v[3])));
      }
      mx = fmaxf(mx, __shfl_xor(mx, 16));
      mx = fmaxf(mx, __shfl_xor(mx, 32));
      if (lane < 4) pmaxw[lane * 2 + mw] = mx;   // scaled s-max per half
    }
    __syncthreads();

    // ---- F: PV out^T = H_head^T @ P^T; den accumulated in-register ----
    {
      const int hw = w >> 2, q = w & 3;
      f32x4 acc[4][2] = {};
      float den[2] = {0.f, 0.f};
      float dvv[2], nml[2];
      int ib[2];
      const float smax = fmaxf(pmaxw[hw * 2], pmaxw[hw * 2 + 1]);
      #pragma unroll
      for (int ni = 0; ni < 2; ++ni) {
        int i = q * 32 + ni * 16 + l15;
        ib[ni] = hw * 128 + i;
        dvv[ni] = dbuf[ib[ni]];                 // scaled d_i
        float tm = smax + dvv[ni];
        nml[ni] = -fmaxf(tm, 0.2f * tm);        // -ml (scaled, post-LR)
      }
      #pragma unroll
      for (int ks = 0; ks < 4; ++ks) {
        const int j0 = ks * 32 + lg * 8;
        float sj[8];
        #pragma unroll
        for (int jj = 0; jj < 8; ++jj) sj[jj] = sbuf[hw * 128 + j0 + jj];
        short8 afr[4];
        #pragma unroll
        for (int mi = 0; mi < 4; ++mi)
          afr[mi] = *(const short8*)(smem + HT + ht_byte(hw * 64 + mi * 16 + l15, j0));
        short8 bfr[2];
        #pragma unroll
        for (int ni = 0; ni < 2; ++ni) {
          float e[8];
          #pragma unroll
          for (int jj = 0; jj < 8; ++jj) {
            float t = sj[jj] + dvv[ni];
            t = fmaxf(t, 0.2f * t);
            e[jj] = exp2f(t + nml[ni]);
          }
          den[ni] += ((e[0] + e[1]) + (e[2] + e[3])) + ((e[4] + e[5]) + (e[6] + e[7]));
          union { short8 s; unsigned int u[4]; } pk;
          #pragma unroll
          for (int t2 = 0; t2 < 4; ++t2) pk.u[t2] = pk2(e[2 * t2], e[2 * t2 + 1]);
          bfr[ni] = pk.s;
        }
        #pragma unroll
        for (int mi = 0; mi < 4; ++mi)
          #pragma unroll
          for (int ni = 0; ni < 2; ++ni)
            acc[mi][ni] = __builtin_amdgcn_mfma_f32_16x16x32_bf16(
                afr[mi], bfr[ni], acc[mi][ni], 0, 0, 0);
      }
      // full denominator: reduce partial sums over lg groups
      float rvv[2];
      #pragma unroll
      for (int ni = 0; ni < 2; ++ni) {
        float d2 = den[ni];
        d2 += __shfl_xor(d2, 16);
        d2 += __shfl_xor(d2, 32);
        rvv[ni] = 1.f / d2;
      }
      if (l < 2) {
        // D: row=feature c, col=node i. out = r_i*acc + bias -> next Xs.
        #pragma unroll
        for (int mi = 0; mi < 4; ++mi) {
          int c0 = hw * 64 + mi * 16 + lg * 4;
          float b0v = bsb[c0], b1v = bsb[c0 + 1], b2v = bsb[c0 + 2], b3v = bsb[c0 + 3];
          #pragma unroll
          for (int ni = 0; ni < 2; ++ni) {
            int i = q * 32 + ni * 16 + l15;
            float r = rvv[ni];
            uint2 u = { pk2(fmaf(acc[mi][ni][0], r, b0v), fmaf(acc[mi][ni][1], r, b1v)),
                        pk2(fmaf(acc[mi][ni][2], r, b2v), fmaf(acc[mi][ni][3], r, b3v)) };
            *(uint2*)(smem + XS + xs_byte(i, c0)) = u;
          }
        }
      } else {
        // final layer: sum over nodes i (ni-sum, shfl over l15, atomic over q)
        #pragma unroll
        for (int mi = 0; mi < 4; ++mi) {
          #pragma unroll
          for (int reg = 0; reg < 4; ++reg) {
            float pv2 = acc[mi][0][reg] * rvv[0] + acc[mi][1][reg] * rvv[1];
            pv2 += __shfl_xor(pv2, 1);
            pv2 += __shfl_xor(pv2, 2);
            pv2 += __shfl_xor(pv2, 4);
            pv2 += __shfl_xor(pv2, 8);
            if (l15 == 0)
              atomicAdd(&oac[hw * 64 + mi * 16 + lg * 4 + reg], pv2);
          }
        }
      }
    }
    __syncthreads();
  }

  // bias summed over 128 nodes = 128*b[c]
  if (tid < 256) out[(size_t)b * 256 + tid] = oac[tid] + 128.f * bsb[tid];
}

extern "C" void kernel_launch(void* const* d_in, const int* in_sizes, int n_in,
                              void* d_out, int out_size, void* d_ws, size_t ws_size,
                              hipStream_t stream) {
  const float* x   = (const float*)d_in[0];
  // d_in[1] = batch_mask (unused: uniform graph layout)
  const float* W0  = (const float*)d_in[2];
  const float* as0 = (const float*)d_in[3];
  const float* ad0 = (const float*)d_in[4];
  const float* b0  = (const float*)d_in[5];
  const float* W1  = (const float*)d_in[6];
  const float* as1 = (const float*)d_in[7];
  const float* ad1 = (const float*)d_in[8];
  const float* b1  = (const float*)d_in[9];
  const float* W2  = (const float*)d_in[10];
  const float* as2 = (const float*)d_in[11];
  const float* ad2 = (const float*)d_in[12];
  const float* b2  = (const float*)d_in[13];
  u16* wt = (u16*)d_ws;                      // 348,160 bytes used

  hipLaunchKernelGGL(prep_w, dim3(100), dim3(256), 0, stream,
                     W0, W1, W2, as0, ad0, as1, ad1, as2, ad2, wt);
  hipLaunchKernelGGL(gat_all, dim3(512), dim3(1024), 0, stream,
                     x, wt, b0, b1, b2, (float*)d_out);
}